// Round 1
// baseline (711.922 us; speedup 1.0000x reference)
//
#include <hip/hip_runtime.h>
#include <math.h>

#define D_ 64
#define DIM_ 256
#define NH_ 4
#define NN_ 65
#define SEC_ 11
#define B_ 4096
#define EDIM_ 82689

// ws layout (float offsets)
#define OFF_R       0
#define OFF_E       512
#define OFF_SALL    (OFF_E + 82944)
#define OFF_XS      (OFF_SALL + 704)
#define OFF_A       (OFF_XS + 262144)
#define OFF_C       (OFF_A + 16640)
#define OFF_AA      (OFF_C + 16640)
#define OFF_AC      (OFF_AA + 16900)
#define OFF_CC      (OFF_AC + 16900)
#define OFF_W2      (OFF_CC + 16900)
#define OFF_AW      (OFF_W2 + 256)
#define OFF_CW      (OFF_AW + 260)
#define OFF_CONST   (OFF_CW + 260)
#define OFF_PART    (OFF_CONST + 4)

// ---------------- K1: LSTM head -> r[512], plus per-sector table ----------------
__global__ void k1_tiny(const float* __restrict__ z, const float* __restrict__ emb,
                        const float* __restrict__ Wsp, const float* __restrict__ bsp,
                        const float* __restrict__ Wh, const float* __restrict__ bh,
                        const float* __restrict__ Wc, const float* __restrict__ bc,
                        const float* __restrict__ Wi, const float* __restrict__ bi,
                        const float* __restrict__ W_ih, const float* __restrict__ W_hh,
                        const float* __restrict__ b_ih, const float* __restrict__ b_hh,
                        const float* __restrict__ W1, const float* __restrict__ b1,
                        float* __restrict__ ws) {
  __shared__ float sz[64], sh0[64], sc0[64], sinp[64], sgates[256], sh[64];
  int t = threadIdx.x;
  if (t < 64) sz[t] = z[t];
  __syncthreads();
  if (t < 192) {
    int d = t & 63; int which = t >> 6;
    const float* W = which == 0 ? Wh : (which == 1 ? Wc : Wi);
    const float* bv = which == 0 ? bh : (which == 1 ? bc : bi);
    float acc = bv[d];
    for (int k = 0; k < 64; ++k) acc = fmaf(sz[k], W[d * 64 + k], acc);
    float tv = tanhf(acc);
    if (which == 0) sh0[d] = tv; else if (which == 1) sc0[d] = tv; else sinp[d] = tv;
  }
  __syncthreads();
  {
    int g = t;
    float acc = b_ih[g] + b_hh[g];
    for (int k = 0; k < 64; ++k) acc = fmaf(sinp[k], W_ih[g * 64 + k], acc);
    for (int k = 0; k < 64; ++k) acc = fmaf(sh0[k], W_hh[g * 64 + k], acc);
    sgates[g] = acc;
  }
  __syncthreads();
  if (t < 64) {
    float ig = sgates[t], fg = sgates[64 + t], gg = sgates[128 + t], og = sgates[192 + t];
    float sf = 1.0f / (1.0f + expf(-fg));
    float si = 1.0f / (1.0f + expf(-ig));
    float so = 1.0f / (1.0f + expf(-og));
    float c = sf * sc0[t] + si * tanhf(gg);
    sh[t] = so * tanhf(c);
  }
  __syncthreads();
  for (int j = t; j < 512; j += 256) {
    float acc = b1[j];
    for (int k = 0; k < 64; ++k) acc = fmaf(sh[k], W1[j * 64 + k], acc);
    ws[OFF_R + j] = fmaxf(acc, 0.0f);
  }
  for (int idx = t; idx < SEC_ * 64; idx += 256) {
    int sec = idx >> 6, d = idx & 63;
    float acc = bsp[d];
    for (int k = 0; k < 256; ++k) acc = fmaf(emb[sec * 256 + k], Wsp[d * 256 + k], acc);
    ws[OFF_SALL + idx] = acc;
  }
}

// ---------------- K2: E = r @ W2^T + b2 (wave per row) ----------------
__global__ __launch_bounds__(256) void k2_E(const float* __restrict__ W2,
                                            const float* __restrict__ b2,
                                            const float* __restrict__ r,
                                            float* __restrict__ E) {
  int lane = threadIdx.x & 63;
  int wave = threadIdx.x >> 6;
  int wg = blockIdx.x * 4 + wave;
  float4 r0 = ((const float4*)r)[lane];
  float4 r1 = ((const float4*)r)[64 + lane];
  int row0 = wg * 8;
  for (int rr = 0; rr < 8; ++rr) {
    int row = row0 + rr;
    if (row >= EDIM_) break;
    const float4* w = (const float4*)(W2 + (size_t)row * 512);
    float4 w0 = w[lane];
    float4 w1 = w[64 + lane];
    float acc = w0.x * r0.x + w0.y * r0.y + w0.z * r0.z + w0.w * r0.w
              + w1.x * r1.x + w1.y * r1.y + w1.z * r1.z + w1.w * r1.w;
    for (int off = 32; off; off >>= 1) acc += __shfl_xor(acc, off);
    if (lane == 0) E[row] = acc + b2[row];
  }
}

// ---------------- K3: w2 = ow@om, scalar const ----------------
__global__ void k3_w2(const float* __restrict__ E, const float* __restrict__ cls,
                      float* __restrict__ ws) {
  __shared__ float som[256];
  __shared__ float red[256];
  int t = threadIdx.x;
  som[t] = E[82432 + t];
  __syncthreads();
  float acc = 0.0f;
  const float* owrow = E + 16640 + t * 256;
  for (int j = 0; j < 256; ++j) acc = fmaf(owrow[j], som[j], acc);
  ws[OFF_W2 + t] = acc;
  red[t] = (E[82176 + t] + cls[t]) * som[t];
  __syncthreads();
  for (int s = 128; s; s >>= 1) {
    if (t < s) red[t] += red[t + s];
    __syncthreads();
  }
  if (t == 0) ws[OFF_CONST] = red[0] + E[82688];
}

// ---------------- K4: Xs = X + s_all[sector] ----------------
__global__ void k4_xs(const float* __restrict__ X, const int* __restrict__ sector,
                      const float* __restrict__ sall, float* __restrict__ Xs) {
  int idx = blockIdx.x * 256 + threadIdx.x;
  int b = idx >> 6, d = idx & 63;
  Xs[idx] = X[idx] + sall[sector[b] * 64 + d];
}

// ---------------- K3a: A = qw*num_w, C = qw*num_b (row0 special) ----------------
__global__ void k3a_ac(const float* __restrict__ E, const float* __restrict__ num_w,
                       const float* __restrict__ num_b, const float* __restrict__ cls,
                       float* __restrict__ A, float* __restrict__ C) {
  int j = blockIdx.x;
  int c = threadIdx.x;
  float qw = E[j * 256 + c];
  if (j == 0) {
    A[c] = 0.0f;
    C[c] = qw * cls[c];
  } else {
    A[j * 256 + c] = qw * num_w[(j - 1) * 256 + c];
    C[j * 256 + c] = qw * num_b[(j - 1) * 256 + c];
  }
}

// ---------------- K3b: per-head coefficient matrices ----------------
__global__ void k3b_coef(const float* __restrict__ A, const float* __restrict__ C,
                         const float* __restrict__ w2, float* __restrict__ AA,
                         float* __restrict__ AC, float* __restrict__ CC,
                         float* __restrict__ aw, float* __restrict__ cw) {
  int i = blockIdx.x;   // 0..64
  int h = blockIdx.y;   // 0..3
  __shared__ float sAi[64], sCi[64];
  int t = threadIdx.x;  // 128
  if (t < 64) {
    sAi[t] = A[i * 256 + h * 64 + t];
    sCi[t] = C[i * 256 + h * 64 + t];
  }
  __syncthreads();
  if (t < 65) {
    int j = t;
    const float* Aj = A + j * 256 + h * 64;
    const float* Cj = C + j * 256 + h * 64;
    float aa = 0.0f, ac = 0.0f, cc = 0.0f;
    for (int c = 0; c < 64; ++c) {
      float ajc = Aj[c], cjc = Cj[c];
      aa = fmaf(sAi[c], ajc, aa);
      ac = fmaf(sAi[c], cjc, ac);
      cc = fmaf(sCi[c], cjc, cc);
    }
    int base = h * 4225 + i * 65 + j;
    AA[base] = 0.125f * aa;
    AC[base] = 0.125f * ac;
    CC[base] = 0.125f * cc;
    if (i == 0) {
      const float* wh = w2 + h * 64;
      float a_ = 0.0f, c_ = 0.0f;
      for (int c = 0; c < 64; ++c) {
        a_ = fmaf(Aj[c], wh[c], a_);
        c_ = fmaf(Cj[c], wh[c], c_);
      }
      aw[h * 65 + j] = a_;
      cw[h * 65 + j] = c_;
    }
  }
}

// ---------------- K5: main attention + softmax + row0 scalar ----------------
#define MB_ 8
__global__ __launch_bounds__(256) void k5_attn(const float* __restrict__ ws,
                                               float* __restrict__ out,
                                               float* __restrict__ partial) {
  __shared__ float sAA[4225], sAC[4225], sCC[4225];
  __shared__ float sx[MB_ * 65], saw[65], scw[65];
  int t = threadIdx.x;
  int h = blockIdx.y;
  int b0 = blockIdx.x * MB_;
  const float* gAA = ws + OFF_AA + h * 4225;
  const float* gAC = ws + OFF_AC + h * 4225;
  const float* gCC = ws + OFF_CC + h * 4225;
  for (int idx = t; idx < 4225; idx += 256) {
    sAA[idx] = gAA[idx];
    sAC[idx] = gAC[idx];
    sCC[idx] = gCC[idx];
  }
  if (t < 65) {
    saw[t] = ws[OFF_AW + h * 65 + t];
    scw[t] = ws[OFF_CW + h * 65 + t];
  }
  const float* Xs = ws + OFF_XS;
  for (int idx = t; idx < MB_ * 64; idx += 256) {
    int bb = idx >> 6, d = idx & 63;
    sx[bb * 65 + 1 + d] = Xs[(size_t)(b0 + bb) * 64 + d];
  }
  if (t < MB_) sx[t * 65] = 0.0f;
  __syncthreads();
  int lane = t & 63, wave = t >> 6;
  for (int bb = 0; bb < MB_; ++bb) {
    const float* xr = sx + bb * 65;
    float x64 = xr[64];
    size_t obase = 4096 + (size_t)((b0 + bb) * NH_ + h) * 4225;
    for (int i = wave; i < 65; i += 4) {
      float xi = xr[i];
      int i65 = i * 65;
      int j = lane;
      float xj = xr[j];
      float v = fmaf(xi, fmaf(xj, sAA[i65 + j], sAC[i65 + j]),
                     fmaf(xj, sAC[j * 65 + i], sCC[i65 + j]));
      float v64 = fmaf(xi, fmaf(x64, sAA[i65 + 64], sAC[i65 + 64]),
                       fmaf(x64, sAC[64 * 65 + i], sCC[i65 + 64]));
      float m = v;
      for (int off = 32; off; off >>= 1) m = fmaxf(m, __shfl_xor(m, off));
      m = fmaxf(m, v64);
      float e = __expf(v - m);
      float e64 = __expf(v64 - m);
      float s = e;
      for (int off = 32; off; off >>= 1) s += __shfl_xor(s, off);
      s += e64;
      float inv = 1.0f / s;
      out[obase + i65 + j] = e * inv;
      if (lane == 0) out[obase + i65 + 64] = e64 * inv;
      if (i == 0) {
        float p = (e * inv) * fmaf(xj, saw[j], scw[j]);
        for (int off = 32; off; off >>= 1) p += __shfl_xor(p, off);
        p += (e64 * inv) * fmaf(x64, saw[64], scw[64]);
        if (lane == 0) partial[(size_t)(b0 + bb) * NH_ + h] = p;
      }
    }
  }
}

// ---------------- K6: final scalar per batch ----------------
__global__ void k6_final(const float* __restrict__ partial, const float* __restrict__ cst,
                         float* __restrict__ out) {
  int b = blockIdx.x * 256 + threadIdx.x;
  if (b < B_) {
    out[b] = partial[b * 4] + partial[b * 4 + 1] + partial[b * 4 + 2] + partial[b * 4 + 3]
           + cst[0];
  }
}

extern "C" void kernel_launch(void* const* d_in, const int* in_sizes, int n_in,
                              void* d_out, int out_size, void* d_ws, size_t ws_size,
                              hipStream_t stream) {
  const float* X     = (const float*)d_in[0];
  const float* z     = (const float*)d_in[1];
  const int*   sector= (const int*)d_in[2];
  const float* emb   = (const float*)d_in[3];
  const float* Wsp   = (const float*)d_in[4];
  const float* bsp   = (const float*)d_in[5];
  const float* Wh    = (const float*)d_in[6];
  const float* bh    = (const float*)d_in[7];
  const float* Wc    = (const float*)d_in[8];
  const float* bc    = (const float*)d_in[9];
  const float* Wi    = (const float*)d_in[10];
  const float* bi    = (const float*)d_in[11];
  const float* W_ih  = (const float*)d_in[12];
  const float* W_hh  = (const float*)d_in[13];
  const float* b_ih  = (const float*)d_in[14];
  const float* b_hh  = (const float*)d_in[15];
  const float* num_w = (const float*)d_in[16];
  const float* num_b = (const float*)d_in[17];
  const float* cls   = (const float*)d_in[18];
  const float* W1    = (const float*)d_in[19];
  const float* b1    = (const float*)d_in[20];
  const float* W2    = (const float*)d_in[21];
  const float* b2    = (const float*)d_in[22];
  float* ws  = (float*)d_ws;
  float* out = (float*)d_out;

  k1_tiny<<<1, 256, 0, stream>>>(z, emb, Wsp, bsp, Wh, bh, Wc, bc, Wi, bi,
                                 W_ih, W_hh, b_ih, b_hh, W1, b1, ws);
  k4_xs<<<1024, 256, 0, stream>>>(X, sector, ws + OFF_SALL, ws + OFF_XS);
  k2_E<<<2592, 256, 0, stream>>>(W2, b2, ws + OFF_R, ws + OFF_E);
  k3_w2<<<1, 256, 0, stream>>>(ws + OFF_E, cls, ws);
  k3a_ac<<<65, 256, 0, stream>>>(ws + OFF_E, num_w, num_b, cls, ws + OFF_A, ws + OFF_C);
  dim3 g3b(65, 4);
  k3b_coef<<<g3b, 128, 0, stream>>>(ws + OFF_A, ws + OFF_C, ws + OFF_W2,
                                    ws + OFF_AA, ws + OFF_AC, ws + OFF_CC,
                                    ws + OFF_AW, ws + OFF_CW);
  dim3 g5(B_ / MB_, NH_);
  k5_attn<<<g5, 256, 0, stream>>>(ws, out, ws + OFF_PART);
  k6_final<<<16, 256, 0, stream>>>(ws + OFF_PART, ws + OFF_CONST, out);
}

// Round 2
// 539.255 us; speedup vs baseline: 1.3202x; 1.3202x over previous
//
#include <hip/hip_runtime.h>
#include <math.h>

#define D_ 64
#define DIM_ 256
#define NH_ 4
#define NN_ 65
#define SEC_ 11
#define B_ 4096
#define EDIM_ 82689

// ws layout (float offsets)
#define OFF_R       0
#define OFF_E       512
#define OFF_SALL    (OFF_E + 82944)
#define OFF_XS      (OFF_SALL + 704)
#define OFF_A       (OFF_XS + 262144)
#define OFF_C       (OFF_A + 16640)
#define OFF_AA      (OFF_C + 16640)
#define OFF_AC      (OFF_AA + 16900)
#define OFF_CC      (OFF_AC + 16900)
#define OFF_W2      (OFF_CC + 16900)
#define OFF_AW      (OFF_W2 + 256)
#define OFF_CW      (OFF_AW + 260)
#define OFF_CONST   (OFF_CW + 260)
#define OFF_PART    (OFF_CONST + 4)

// ---------------- KA: block 0 = LSTM head -> r[512]; blocks 1..11 = sector table ----
__global__ __launch_bounds__(256) void kA(const float* __restrict__ z, const float* __restrict__ emb,
                        const float* __restrict__ Wsp, const float* __restrict__ bsp,
                        const float* __restrict__ Wh, const float* __restrict__ bh,
                        const float* __restrict__ Wc, const float* __restrict__ bc,
                        const float* __restrict__ Wi, const float* __restrict__ bi,
                        const float* __restrict__ W_ih, const float* __restrict__ W_hh,
                        const float* __restrict__ b_ih, const float* __restrict__ b_hh,
                        const float* __restrict__ W1, const float* __restrict__ b1,
                        float* __restrict__ ws) {
  __shared__ float sz[64], sh0[64], sc0[64], sinp[64], sgates[256], sh[64];
  int t = threadIdx.x;
  if (blockIdx.x == 0) {
    if (t < 64) sz[t] = z[t];
    __syncthreads();
    if (t < 192) {
      int d = t & 63; int which = t >> 6;
      const float* W = which == 0 ? Wh : (which == 1 ? Wc : Wi);
      const float* bv = which == 0 ? bh : (which == 1 ? bc : bi);
      float acc = bv[d];
      for (int k = 0; k < 64; ++k) acc = fmaf(sz[k], W[d * 64 + k], acc);
      float tv = tanhf(acc);
      if (which == 0) sh0[d] = tv; else if (which == 1) sc0[d] = tv; else sinp[d] = tv;
    }
    __syncthreads();
    {
      int g = t;
      float acc = b_ih[g] + b_hh[g];
      for (int k = 0; k < 64; ++k) acc = fmaf(sinp[k], W_ih[g * 64 + k], acc);
      for (int k = 0; k < 64; ++k) acc = fmaf(sh0[k], W_hh[g * 64 + k], acc);
      sgates[g] = acc;
    }
    __syncthreads();
    if (t < 64) {
      float ig = sgates[t], fg = sgates[64 + t], gg = sgates[128 + t], og = sgates[192 + t];
      float sf = 1.0f / (1.0f + expf(-fg));
      float si = 1.0f / (1.0f + expf(-ig));
      float so = 1.0f / (1.0f + expf(-og));
      float c = sf * sc0[t] + si * tanhf(gg);
      sh[t] = so * tanhf(c);
    }
    __syncthreads();
    for (int j = t; j < 512; j += 256) {
      float acc = b1[j];
      for (int k = 0; k < 64; ++k) acc = fmaf(sh[k], W1[j * 64 + k], acc);
      ws[OFF_R + j] = fmaxf(acc, 0.0f);
    }
  } else {
    // sector table: s_all[sec] = emb[sec] @ Wsp.T + bsp
    int sec = blockIdx.x - 1;
    int lane = t & 63, wave = t >> 6;
    float e0 = emb[sec * 256 + lane];
    float e1 = emb[sec * 256 + 64 + lane];
    float e2 = emb[sec * 256 + 128 + lane];
    float e3 = emb[sec * 256 + 192 + lane];
    for (int dd = 0; dd < 16; ++dd) {
      int d = wave * 16 + dd;
      const float* wr = Wsp + d * 256;
      float acc = fmaf(wr[lane], e0,
                  fmaf(wr[64 + lane], e1,
                  fmaf(wr[128 + lane], e2, wr[192 + lane] * e3)));
      for (int off = 32; off; off >>= 1) acc += __shfl_xor(acc, off);
      if (lane == 0) ws[OFF_SALL + sec * 64 + d] = acc + bsp[d];
    }
  }
}

// ---------------- K2: E = r @ W2^T + b2 (wave per row, 8 rows unrolled) ----------------
__global__ __launch_bounds__(256) void k2_E(const float* __restrict__ W2,
                                            const float* __restrict__ b2,
                                            const float* __restrict__ r,
                                            float* __restrict__ E) {
  int lane = threadIdx.x & 63;
  int wave = threadIdx.x >> 6;
  int row0 = (blockIdx.x * 4 + wave) * 8;
  float4 r0 = ((const float4*)r)[lane];
  float4 r1 = ((const float4*)r)[64 + lane];
  float acc[8];
  #pragma unroll
  for (int rr = 0; rr < 8; ++rr) {
    int row = row0 + rr;
    float4 w0 = make_float4(0.f, 0.f, 0.f, 0.f), w1 = w0;
    if (row < EDIM_) {
      const float4* w = (const float4*)(W2 + (size_t)row * 512);
      w0 = w[lane];
      w1 = w[64 + lane];
    }
    acc[rr] = w0.x * r0.x + w0.y * r0.y + w0.z * r0.z + w0.w * r0.w
            + w1.x * r1.x + w1.y * r1.y + w1.z * r1.z + w1.w * r1.w;
  }
  #pragma unroll
  for (int rr = 0; rr < 8; ++rr)
    for (int off = 32; off; off >>= 1) acc[rr] += __shfl_xor(acc[rr], off);
  #pragma unroll
  for (int rr = 0; rr < 8; ++rr) {
    int row = row0 + rr;
    if (row < EDIM_ && lane == rr) E[row] = acc[rr] + b2[row];
  }
}

// ---------------- KB: blocks 0..64 = A/C; 65..128 = w2 rows; 129 = const ----------------
__global__ __launch_bounds__(256) void kB(const float* __restrict__ E,
                                          const float* __restrict__ num_w,
                                          const float* __restrict__ num_b,
                                          const float* __restrict__ cls,
                                          float* __restrict__ ws) {
  __shared__ float red[256];
  int blk = blockIdx.x, t = threadIdx.x;
  float* A = ws + OFF_A;
  float* C = ws + OFF_C;
  if (blk < 65) {
    int j = blk, c = t;
    float qw = E[j * 256 + c];
    if (j == 0) {
      A[c] = 0.0f;
      C[c] = qw * cls[c];
    } else {
      A[j * 256 + c] = qw * num_w[(j - 1) * 256 + c];
      C[j * 256 + c] = qw * num_b[(j - 1) * 256 + c];
    }
  } else if (blk < 129) {
    int lane = t & 63, wave = t >> 6;
    int row = (blk - 65) * 4 + wave;   // 0..255
    const float* ow = E + 16640 + row * 256;
    const float* om = E + 82432;
    float acc = 0.0f;
    #pragma unroll
    for (int k = 0; k < 4; ++k) acc = fmaf(ow[k * 64 + lane], om[k * 64 + lane], acc);
    for (int off = 32; off; off >>= 1) acc += __shfl_xor(acc, off);
    if (lane == 0) ws[OFF_W2 + row] = acc;
  } else {
    red[t] = (E[82176 + t] + cls[t]) * E[82432 + t];
    __syncthreads();
    for (int s = 128; s; s >>= 1) {
      if (t < s) red[t] += red[t + s];
      __syncthreads();
    }
    if (t == 0) ws[OFF_CONST] = red[0] + E[82688];
  }
}

// ---------------- K4: Xs = X + s_all[sector] ----------------
__global__ void k4_xs(const float* __restrict__ X, const int* __restrict__ sector,
                      const float* __restrict__ sall, float* __restrict__ Xs) {
  int idx = blockIdx.x * 256 + threadIdx.x;
  int b = idx >> 6, d = idx & 63;
  Xs[idx] = X[idx] + sall[sector[b] * 64 + d];
}

// ---------------- K3b: per-head coefficient matrices ----------------
__global__ void k3b_coef(const float* __restrict__ A, const float* __restrict__ C,
                         const float* __restrict__ w2, float* __restrict__ AA,
                         float* __restrict__ AC, float* __restrict__ CC,
                         float* __restrict__ aw, float* __restrict__ cw) {
  int i = blockIdx.x;   // 0..64
  int h = blockIdx.y;   // 0..3
  __shared__ float sAi[64], sCi[64];
  int t = threadIdx.x;  // 128
  if (t < 64) {
    sAi[t] = A[i * 256 + h * 64 + t];
    sCi[t] = C[i * 256 + h * 64 + t];
  }
  __syncthreads();
  if (t < 65) {
    int j = t;
    const float* Aj = A + j * 256 + h * 64;
    const float* Cj = C + j * 256 + h * 64;
    float aa = 0.0f, ac = 0.0f, cc = 0.0f;
    for (int c = 0; c < 64; ++c) {
      float ajc = Aj[c], cjc = Cj[c];
      aa = fmaf(sAi[c], ajc, aa);
      ac = fmaf(sAi[c], cjc, ac);
      cc = fmaf(sCi[c], cjc, cc);
    }
    int base = h * 4225 + i * 65 + j;
    AA[base] = 0.125f * aa;
    AC[base] = 0.125f * ac;
    CC[base] = 0.125f * cc;
    if (i == 0) {
      const float* wh = w2 + h * 64;
      float a_ = 0.0f, c_ = 0.0f;
      for (int c = 0; c < 64; ++c) {
        a_ = fmaf(Aj[c], wh[c], a_);
        c_ = fmaf(Cj[c], wh[c], c_);
      }
      aw[h * 65 + j] = a_;
      cw[h * 65 + j] = c_;
    }
  }
}

// ---------------- K5: two-pass softmax, shuffle-free row sums ----------------
#define MB_ 8
__global__ __launch_bounds__(256) void k5_attn(const float* __restrict__ ws,
                                               float* __restrict__ out,
                                               float* __restrict__ partial) {
  __shared__ float sAA[4225], sAC[4225], sCC[4225];
  __shared__ float sx[MB_ * 65], sinv[MB_ * 65], saw[65], scw[65];
  int t = threadIdx.x;
  int h = blockIdx.y;
  int b0 = blockIdx.x * MB_;
  const float* gAA = ws + OFF_AA + h * 4225;
  const float* gAC = ws + OFF_AC + h * 4225;
  const float* gCC = ws + OFF_CC + h * 4225;
  for (int idx = t; idx < 4225; idx += 256) {
    sAA[idx] = gAA[idx];
    sAC[idx] = gAC[idx];
    sCC[idx] = gCC[idx];
  }
  if (t < 65) {
    saw[t] = ws[OFF_AW + h * 65 + t];
    scw[t] = ws[OFF_CW + h * 65 + t];
  }
  const float* Xs = ws + OFF_XS;
  for (int idx = t; idx < MB_ * 64; idx += 256) {
    int bb = idx >> 6, d = idx & 63;
    sx[bb * 65 + 1 + d] = Xs[(size_t)(b0 + bb) * 64 + d];
  }
  if (t < MB_) sx[t * 65] = 0.0f;
  __syncthreads();
  int lane = t & 63, wave = t >> 6;

  // ---- pass 1: row sums (lane-per-row, no shuffles for rows 0..63) ----
  for (int bb = wave; bb < MB_; bb += 4) {
    const float* xr = sx + bb * 65;
    float xi = xr[lane];   // lane = row index
    float s = 0.0f;
    #pragma unroll 8
    for (int j = 0; j < 65; ++j) {
      float xj = xr[j];                      // broadcast
      float aa = sAA[lane * 65 + j];         // 2-way bank alias: free
      float ac = sAC[lane * 65 + j];
      float act = sAC[j * 65 + lane];        // consecutive: free
      float cc = sCC[lane * 65 + j];
      float v = fmaf(xi, fmaf(xj, aa, ac), fmaf(xj, act, cc));
      s += __expf(v);
    }
    sinv[bb * 65 + lane] = 1.0f / s;
    // row 64: cooperative (6-step reduce, once per batch)
    {
      float x64 = xr[64];
      int j = lane;
      float xj = xr[j];
      float aa = sAA[64 * 65 + j];
      float ac = sAC[64 * 65 + j];
      float act = sAC[j * 65 + 64];
      float cc = sCC[64 * 65 + j];
      float e = __expf(fmaf(x64, fmaf(xj, aa, ac), fmaf(xj, act, cc)));
      for (int off = 32; off; off >>= 1) e += __shfl_xor(e, off);
      float aa4 = sAA[4224], ac4 = sAC[4224], cc4 = sCC[4224];
      e += __expf(fmaf(x64, fmaf(x64, aa4, ac4), fmaf(x64, ac4, cc4)));
      if (lane == 0) sinv[bb * 65 + 64] = 1.0f / e;
    }
  }
  __syncthreads();

  // ---- pass 2: recompute + write (wave-per-row, coefs hoisted over batches) ----
  float xjv[MB_], x64v[MB_];
  #pragma unroll
  for (int bb = 0; bb < MB_; ++bb) {
    xjv[bb] = sx[bb * 65 + lane];
    x64v[bb] = sx[bb * 65 + 64];
  }
  for (int i = wave; i < 65; i += 4) {
    int j = lane;
    float aa = sAA[i * 65 + j];
    float ac = sAC[i * 65 + j];
    float act = sAC[j * 65 + i];
    float cc = sCC[i * 65 + j];
    float aa4 = sAA[i * 65 + 64];
    float ac4 = sAC[i * 65 + 64];
    float act4 = sAC[64 * 65 + i];
    float cc4 = sCC[i * 65 + 64];
    #pragma unroll
    for (int bb = 0; bb < MB_; ++bb) {
      float xi = sx[bb * 65 + i];            // broadcast
      float inv = sinv[bb * 65 + i];         // broadcast
      float xj = xjv[bb], x64 = x64v[bb];
      float e = __expf(fmaf(xi, fmaf(xj, aa, ac), fmaf(xj, act, cc))) * inv;
      float e4 = __expf(fmaf(xi, fmaf(x64, aa4, ac4), fmaf(x64, act4, cc4))) * inv;
      size_t obase = 4096 + (size_t)((b0 + bb) * NH_ + h) * 4225 + (size_t)i * 65;
      out[obase + j] = e;
      if (lane == 0) out[obase + 64] = e4;
      if (i == 0) {
        float p = e * fmaf(xj, saw[j], scw[j]);
        for (int off = 32; off; off >>= 1) p += __shfl_xor(p, off);
        p += e4 * fmaf(x64, saw[64], scw[64]);
        if (lane == 0) partial[(size_t)(b0 + bb) * NH_ + h] = p;
      }
    }
  }
}

// ---------------- K6: final scalar per batch ----------------
__global__ void k6_final(const float* __restrict__ partial, const float* __restrict__ cst,
                         float* __restrict__ out) {
  int b = blockIdx.x * 256 + threadIdx.x;
  if (b < B_) {
    out[b] = partial[b * 4] + partial[b * 4 + 1] + partial[b * 4 + 2] + partial[b * 4 + 3]
           + cst[0];
  }
}

extern "C" void kernel_launch(void* const* d_in, const int* in_sizes, int n_in,
                              void* d_out, int out_size, void* d_ws, size_t ws_size,
                              hipStream_t stream) {
  const float* X     = (const float*)d_in[0];
  const float* z     = (const float*)d_in[1];
  const int*   sector= (const int*)d_in[2];
  const float* emb   = (const float*)d_in[3];
  const float* Wsp   = (const float*)d_in[4];
  const float* bsp   = (const float*)d_in[5];
  const float* Wh    = (const float*)d_in[6];
  const float* bh    = (const float*)d_in[7];
  const float* Wc    = (const float*)d_in[8];
  const float* bc    = (const float*)d_in[9];
  const float* Wi    = (const float*)d_in[10];
  const float* bi    = (const float*)d_in[11];
  const float* W_ih  = (const float*)d_in[12];
  const float* W_hh  = (const float*)d_in[13];
  const float* b_ih  = (const float*)d_in[14];
  const float* b_hh  = (const float*)d_in[15];
  const float* num_w = (const float*)d_in[16];
  const float* num_b = (const float*)d_in[17];
  const float* cls   = (const float*)d_in[18];
  const float* W1    = (const float*)d_in[19];
  const float* b1    = (const float*)d_in[20];
  const float* W2    = (const float*)d_in[21];
  const float* b2    = (const float*)d_in[22];
  float* ws  = (float*)d_ws;
  float* out = (float*)d_out;

  kA<<<12, 256, 0, stream>>>(z, emb, Wsp, bsp, Wh, bh, Wc, bc, Wi, bi,
                             W_ih, W_hh, b_ih, b_hh, W1, b1, ws);
  k4_xs<<<1024, 256, 0, stream>>>(X, sector, ws + OFF_SALL, ws + OFF_XS);
  k2_E<<<2585, 256, 0, stream>>>(W2, b2, ws + OFF_R, ws + OFF_E);
  kB<<<130, 256, 0, stream>>>(ws + OFF_E, num_w, num_b, cls, ws);
  dim3 g3b(65, 4);
  k3b_coef<<<g3b, 128, 0, stream>>>(ws + OFF_A, ws + OFF_C, ws + OFF_W2,
                                    ws + OFF_AA, ws + OFF_AC, ws + OFF_CC,
                                    ws + OFF_AW, ws + OFF_CW);
  dim3 g5(B_ / MB_, NH_);
  k5_attn<<<g5, 256, 0, stream>>>(ws, out, ws + OFF_PART);
  k6_final<<<16, 256, 0, stream>>>(ws + OFF_PART, ws + OFF_CONST, out);
}

// Round 3
// 529.276 us; speedup vs baseline: 1.3451x; 1.0189x over previous
//
#include <hip/hip_runtime.h>
#include <math.h>

#define D_ 64
#define DIM_ 256
#define NH_ 4
#define NN_ 65
#define SEC_ 11
#define B_ 4096
#define EDIM_ 82689

// ws layout (float offsets)
#define OFF_R       0
#define OFF_E       512
#define OFF_SALL    (OFF_E + 82944)
#define OFF_A       (OFF_SALL + 704)
#define OFF_C       (OFF_A + 16640)
#define OFF_AA      (OFF_C + 16640)
#define OFF_AC      (OFF_AA + 16900)
#define OFF_CC      (OFF_AC + 16900)
#define OFF_W2      (OFF_CC + 16900)
#define OFF_AW      (OFF_W2 + 256)
#define OFF_CW      (OFF_AW + 260)
#define OFF_CONST   (OFF_CW + 260)
#define OFF_PART    (OFF_CONST + 4)

// ---------------- KA: block 0 = LSTM head -> r[512]; blocks 1..11 = sector table ----
__global__ __launch_bounds__(256) void kA(const float* __restrict__ z, const float* __restrict__ emb,
                        const float* __restrict__ Wsp, const float* __restrict__ bsp,
                        const float* __restrict__ Wh, const float* __restrict__ bh,
                        const float* __restrict__ Wc, const float* __restrict__ bc,
                        const float* __restrict__ Wi, const float* __restrict__ bi,
                        const float* __restrict__ W_ih, const float* __restrict__ W_hh,
                        const float* __restrict__ b_ih, const float* __restrict__ b_hh,
                        const float* __restrict__ W1, const float* __restrict__ b1,
                        float* __restrict__ ws) {
  __shared__ float sz[64], sh0[64], sc0[64], sinp[64], sgates[256], sh[64];
  int t = threadIdx.x;
  if (blockIdx.x == 0) {
    if (t < 64) sz[t] = z[t];
    __syncthreads();
    if (t < 192) {
      int d = t & 63; int which = t >> 6;
      const float* W = which == 0 ? Wh : (which == 1 ? Wc : Wi);
      const float* bv = which == 0 ? bh : (which == 1 ? bc : bi);
      float acc = bv[d];
      for (int k = 0; k < 64; ++k) acc = fmaf(sz[k], W[d * 64 + k], acc);
      float tv = tanhf(acc);
      if (which == 0) sh0[d] = tv; else if (which == 1) sc0[d] = tv; else sinp[d] = tv;
    }
    __syncthreads();
    {
      int g = t;
      float acc = b_ih[g] + b_hh[g];
      for (int k = 0; k < 64; ++k) acc = fmaf(sinp[k], W_ih[g * 64 + k], acc);
      for (int k = 0; k < 64; ++k) acc = fmaf(sh0[k], W_hh[g * 64 + k], acc);
      sgates[g] = acc;
    }
    __syncthreads();
    if (t < 64) {
      float ig = sgates[t], fg = sgates[64 + t], gg = sgates[128 + t], og = sgates[192 + t];
      float sf = 1.0f / (1.0f + expf(-fg));
      float si = 1.0f / (1.0f + expf(-ig));
      float so = 1.0f / (1.0f + expf(-og));
      float c = sf * sc0[t] + si * tanhf(gg);
      sh[t] = so * tanhf(c);
    }
    __syncthreads();
    for (int j = t; j < 512; j += 256) {
      float acc = b1[j];
      for (int k = 0; k < 64; ++k) acc = fmaf(sh[k], W1[j * 64 + k], acc);
      ws[OFF_R + j] = fmaxf(acc, 0.0f);
    }
  } else {
    int sec = blockIdx.x - 1;
    int lane = t & 63, wave = t >> 6;
    float e0 = emb[sec * 256 + lane];
    float e1 = emb[sec * 256 + 64 + lane];
    float e2 = emb[sec * 256 + 128 + lane];
    float e3 = emb[sec * 256 + 192 + lane];
    for (int dd = 0; dd < 16; ++dd) {
      int d = wave * 16 + dd;
      const float* wr = Wsp + d * 256;
      float acc = fmaf(wr[lane], e0,
                  fmaf(wr[64 + lane], e1,
                  fmaf(wr[128 + lane], e2, wr[192 + lane] * e3)));
      for (int off = 32; off; off >>= 1) acc += __shfl_xor(acc, off);
      if (lane == 0) ws[OFF_SALL + sec * 64 + d] = acc + bsp[d];
    }
  }
}

// ---------------- K2: E = r @ W2^T + b2 (wave per row, 8 rows unrolled) ----------------
__global__ __launch_bounds__(256) void k2_E(const float* __restrict__ W2,
                                            const float* __restrict__ b2,
                                            const float* __restrict__ r,
                                            float* __restrict__ E) {
  int lane = threadIdx.x & 63;
  int wave = threadIdx.x >> 6;
  int row0 = (blockIdx.x * 4 + wave) * 8;
  float4 r0 = ((const float4*)r)[lane];
  float4 r1 = ((const float4*)r)[64 + lane];
  float acc[8];
  #pragma unroll
  for (int rr = 0; rr < 8; ++rr) {
    int row = row0 + rr;
    float4 w0 = make_float4(0.f, 0.f, 0.f, 0.f), w1 = w0;
    if (row < EDIM_) {
      const float4* w = (const float4*)(W2 + (size_t)row * 512);
      w0 = w[lane];
      w1 = w[64 + lane];
    }
    acc[rr] = w0.x * r0.x + w0.y * r0.y + w0.z * r0.z + w0.w * r0.w
            + w1.x * r1.x + w1.y * r1.y + w1.z * r1.z + w1.w * r1.w;
  }
  #pragma unroll
  for (int rr = 0; rr < 8; ++rr)
    for (int off = 32; off; off >>= 1) acc[rr] += __shfl_xor(acc[rr], off);
  #pragma unroll
  for (int rr = 0; rr < 8; ++rr) {
    int row = row0 + rr;
    if (row < EDIM_ && lane == rr) E[row] = acc[rr] + b2[row];
  }
}

// ---------------- KB: blocks 0..64 = A/C; 65..128 = w2 rows; 129 = const ----------------
__global__ __launch_bounds__(256) void kB(const float* __restrict__ E,
                                          const float* __restrict__ num_w,
                                          const float* __restrict__ num_b,
                                          const float* __restrict__ cls,
                                          float* __restrict__ ws) {
  __shared__ float red[256];
  int blk = blockIdx.x, t = threadIdx.x;
  float* A = ws + OFF_A;
  float* C = ws + OFF_C;
  if (blk < 65) {
    int j = blk, c = t;
    float qw = E[j * 256 + c];
    if (j == 0) {
      A[c] = 0.0f;
      C[c] = qw * cls[c];
    } else {
      A[j * 256 + c] = qw * num_w[(j - 1) * 256 + c];
      C[j * 256 + c] = qw * num_b[(j - 1) * 256 + c];
    }
  } else if (blk < 129) {
    int lane = t & 63, wave = t >> 6;
    int row = (blk - 65) * 4 + wave;
    const float* ow = E + 16640 + row * 256;
    const float* om = E + 82432;
    float acc = 0.0f;
    #pragma unroll
    for (int k = 0; k < 4; ++k) acc = fmaf(ow[k * 64 + lane], om[k * 64 + lane], acc);
    for (int off = 32; off; off >>= 1) acc += __shfl_xor(acc, off);
    if (lane == 0) ws[OFF_W2 + row] = acc;
  } else {
    red[t] = (E[82176 + t] + cls[t]) * E[82432 + t];
    __syncthreads();
    for (int s = 128; s; s >>= 1) {
      if (t < s) red[t] += red[t + s];
      __syncthreads();
    }
    if (t == 0) ws[OFF_CONST] = red[0] + E[82688];
  }
}

// ---------------- K3b: per-head coefficient matrices ----------------
__global__ void k3b_coef(const float* __restrict__ A, const float* __restrict__ C,
                         const float* __restrict__ w2, float* __restrict__ AA,
                         float* __restrict__ AC, float* __restrict__ CC,
                         float* __restrict__ aw, float* __restrict__ cw) {
  int i = blockIdx.x;   // 0..64
  int h = blockIdx.y;   // 0..3
  __shared__ float sAi[64], sCi[64];
  int t = threadIdx.x;  // 128
  if (t < 64) {
    sAi[t] = A[i * 256 + h * 64 + t];
    sCi[t] = C[i * 256 + h * 64 + t];
  }
  __syncthreads();
  if (t < 65) {
    int j = t;
    const float* Aj = A + j * 256 + h * 64;
    const float* Cj = C + j * 256 + h * 64;
    float aa = 0.0f, ac = 0.0f, cc = 0.0f;
    for (int c = 0; c < 64; ++c) {
      float ajc = Aj[c], cjc = Cj[c];
      aa = fmaf(sAi[c], ajc, aa);
      ac = fmaf(sAi[c], cjc, ac);
      cc = fmaf(sCi[c], cjc, cc);
    }
    int base = h * 4225 + i * 65 + j;
    AA[base] = 0.125f * aa;
    AC[base] = 0.125f * ac;
    CC[base] = 0.125f * cc;
    if (i == 0) {
      const float* wh = w2 + h * 64;
      float a_ = 0.0f, c_ = 0.0f;
      for (int c = 0; c < 64; ++c) {
        a_ = fmaf(Aj[c], wh[c], a_);
        c_ = fmaf(Cj[c], wh[c], c_);
      }
      aw[h * 65 + j] = a_;
      cw[h * 65 + j] = c_;
    }
  }
}

// ---------------- K5: single-pass softmax, wave-per-row, batch-interleaved ----------------
#define MB_ 8
__global__ __launch_bounds__(256) void k5_attn(const float* __restrict__ ws,
                                               const float* __restrict__ X,
                                               const int* __restrict__ sector,
                                               float* __restrict__ out,
                                               float* __restrict__ partial) {
  __shared__ float sAA[4225], sAC[4225], sCC[4225];
  __shared__ float sx[MB_ * 65], saw[65], scw[65];
  int t = threadIdx.x;
  int h = blockIdx.y;
  int b0 = blockIdx.x * MB_;
  const float* gAA = ws + OFF_AA + h * 4225;
  const float* gAC = ws + OFF_AC + h * 4225;
  const float* gCC = ws + OFF_CC + h * 4225;
  for (int idx = t; idx < 4225; idx += 256) {
    sAA[idx] = gAA[idx];
    sAC[idx] = gAC[idx];
    sCC[idx] = gCC[idx];
  }
  if (t < 65) {
    saw[t] = ws[OFF_AW + h * 65 + t];
    scw[t] = ws[OFF_CW + h * 65 + t];
  }
  const float* sall = ws + OFF_SALL;
  for (int idx = t; idx < MB_ * 64; idx += 256) {
    int bb = idx >> 6, d = idx & 63;
    int b = b0 + bb;
    sx[bb * 65 + 1 + d] = X[(size_t)b * 64 + d] + sall[sector[b] * 64 + d];
  }
  if (t < MB_) sx[t * 65] = 0.0f;
  __syncthreads();
  int lane = t & 63, wave = t >> 6;

  float xjv[MB_], x64v[MB_];
  #pragma unroll
  for (int bb = 0; bb < MB_; ++bb) {
    xjv[bb] = sx[bb * 65 + lane];
    x64v[bb] = sx[bb * 65 + 64];
  }
  int j = lane;
  for (int i = wave; i < 65; i += 4) {
    float aa = sAA[i * 65 + j];
    float ac = sAC[i * 65 + j];
    float act = sAC[j * 65 + i];
    float cc = sCC[i * 65 + j];
    float aa4 = sAA[i * 65 + 64];
    float ac4 = sAC[i * 65 + 64];
    float act4 = sAC[64 * 65 + i];
    float cc4 = sCC[i * 65 + 64];
    float e[MB_], e4[MB_], s[MB_];
    #pragma unroll
    for (int bb = 0; bb < MB_; ++bb) {
      float xi = sx[bb * 65 + i];
      float xj = xjv[bb], x64 = x64v[bb];
      e[bb] = __expf(fmaf(xi, fmaf(xj, aa, ac), fmaf(xj, act, cc)));
      e4[bb] = __expf(fmaf(xi, fmaf(x64, aa4, ac4), fmaf(x64, act4, cc4)));
      s[bb] = e[bb];
    }
    // 8 independent butterfly chains -> pipelined
    #pragma unroll
    for (int off = 32; off; off >>= 1) {
      #pragma unroll
      for (int bb = 0; bb < MB_; ++bb) s[bb] += __shfl_xor(s[bb], off);
    }
    #pragma unroll
    for (int bb = 0; bb < MB_; ++bb) {
      float inv = 1.0f / (s[bb] + e4[bb]);
      float p0 = e[bb] * inv;
      float p4 = e4[bb] * inv;
      size_t obase = 4096 + (size_t)((b0 + bb) * NH_ + h) * 4225 + (size_t)i * 65;
      out[obase + j] = p0;
      if (lane == 0) out[obase + 64] = p4;
      if (i == 0) {
        float p = p0 * fmaf(xjv[bb], saw[j], scw[j]);
        #pragma unroll
        for (int off = 32; off; off >>= 1) p += __shfl_xor(p, off);
        p += p4 * fmaf(x64v[bb], saw[64], scw[64]);
        if (lane == 0) partial[(size_t)(b0 + bb) * NH_ + h] = p;
      }
    }
  }
}

// ---------------- K6: final scalar per batch ----------------
__global__ void k6_final(const float* __restrict__ partial, const float* __restrict__ cst,
                         float* __restrict__ out) {
  int b = blockIdx.x * 256 + threadIdx.x;
  if (b < B_) {
    out[b] = partial[b * 4] + partial[b * 4 + 1] + partial[b * 4 + 2] + partial[b * 4 + 3]
           + cst[0];
  }
}

extern "C" void kernel_launch(void* const* d_in, const int* in_sizes, int n_in,
                              void* d_out, int out_size, void* d_ws, size_t ws_size,
                              hipStream_t stream) {
  const float* X     = (const float*)d_in[0];
  const float* z     = (const float*)d_in[1];
  const int*   sector= (const int*)d_in[2];
  const float* emb   = (const float*)d_in[3];
  const float* Wsp   = (const float*)d_in[4];
  const float* bsp   = (const float*)d_in[5];
  const float* Wh    = (const float*)d_in[6];
  const float* bh    = (const float*)d_in[7];
  const float* Wc    = (const float*)d_in[8];
  const float* bc    = (const float*)d_in[9];
  const float* Wi    = (const float*)d_in[10];
  const float* bi    = (const float*)d_in[11];
  const float* W_ih  = (const float*)d_in[12];
  const float* W_hh  = (const float*)d_in[13];
  const float* b_ih  = (const float*)d_in[14];
  const float* b_hh  = (const float*)d_in[15];
  const float* num_w = (const float*)d_in[16];
  const float* num_b = (const float*)d_in[17];
  const float* cls   = (const float*)d_in[18];
  const float* W1    = (const float*)d_in[19];
  const float* b1    = (const float*)d_in[20];
  const float* W2    = (const float*)d_in[21];
  const float* b2    = (const float*)d_in[22];
  float* ws  = (float*)d_ws;
  float* out = (float*)d_out;

  kA<<<12, 256, 0, stream>>>(z, emb, Wsp, bsp, Wh, bh, Wc, bc, Wi, bi,
                             W_ih, W_hh, b_ih, b_hh, W1, b1, ws);
  k2_E<<<2585, 256, 0, stream>>>(W2, b2, ws + OFF_R, ws + OFF_E);
  kB<<<130, 256, 0, stream>>>(ws + OFF_E, num_w, num_b, cls, ws);
  dim3 g3b(65, 4);
  k3b_coef<<<g3b, 128, 0, stream>>>(ws + OFF_A, ws + OFF_C, ws + OFF_W2,
                                    ws + OFF_AA, ws + OFF_AC, ws + OFF_CC,
                                    ws + OFF_AW, ws + OFF_CW);
  dim3 g5(B_ / MB_, NH_);
  k5_attn<<<g5, 256, 0, stream>>>(ws, X, sector, out, ws + OFF_PART);
  k6_final<<<16, 256, 0, stream>>>(ws + OFF_PART, ws + OFF_CONST, out);
}